// Round 2
// baseline (373.272 us; speedup 1.0000x reference)
//
#include <hip/hip_runtime.h>
#include <math.h>

#define NB 32768
#define NT 48
#define NH 32
#define NOH 16
#define NK 3
#define NS 6
#define NSUB 4

typedef float f2 __attribute__((ext_vector_type(2)));

// Force a value/pair to stay live in VGPRs (compiler cannot rematerialize)
#define PIN_V(x) asm volatile("" : "+v"(x))
// Make a wave-uniform float SGPR-resident (legal VGPR->SGPR via readfirstlane)
__device__ __forceinline__ float uni(float x) {
    return __int_as_float(__builtin_amdgcn_readfirstlane(__float_as_int(x)));
}

// packed fma, src0 scalar-broadcast via op_sel (verified semantics in prior session):
//   LO: acc.{x,y} += zp.x * w.{x,y}      HI: acc.{x,y} += zp.y * w.{x,y}
#define PK_FMA_LO(acc, zp, w) \
    asm("v_pk_fma_f32 %0, %1, %2, %0 op_sel:[0,0,0] op_sel_hi:[0,1,1]" \
        : "+v"(acc) : "v"(zp), "v"(w))
#define PK_FMA_HI(acc, zp, w) \
    asm("v_pk_fma_f32 %0, %1, %2, %0 op_sel:[1,0,0] op_sel_hi:[1,1,1]" \
        : "+v"(acc) : "v"(zp), "v"(w))
// init forms: dst = bcast(zp)*w + c   (no accumulator-copy mov)
#define PK_FMA_LO_I(dst, zp, w, c) \
    asm("v_pk_fma_f32 %0, %1, %2, %3 op_sel:[0,0,0] op_sel_hi:[0,1,1]" \
        : "=v"(dst) : "v"(zp), "v"(w), "v"(c))
// swapped src0: lo-result uses zp.hi, hi-result uses zp.lo
#define PK_FMA_SWAP_I(dst, zp, cc, c) \
    asm("v_pk_fma_f32 %0, %1, %2, %3 op_sel:[1,0,0] op_sel_hi:[0,1,1]" \
        : "=v"(dst) : "v"(zp), "v"(cc), "v"(c))

__device__ __forceinline__ f2 fma2(f2 a, f2 b, f2 c) {
    return __builtin_elementwise_fma(a, b, c);
}
__device__ __forceinline__ f2 bc2(float x) { f2 r; r.x = x; r.y = x; return r; }

// partner-lane values via DPP quad_perm — full-rate VALU, stays inside the quad
__device__ __forceinline__ float dpp_xor1(float v) {   // quad_perm [1,0,3,2]
    int x = __builtin_amdgcn_update_dpp(0, __float_as_int(v), 0xB1, 0xF, 0xF, false);
    return __int_as_float(x);
}
__device__ __forceinline__ float dpp_xor2(float v) {   // quad_perm [2,3,0,1]
    int x = __builtin_amdgcn_update_dpp(0, __float_as_int(v), 0x4E, 0xF, 0xF, false);
    return __int_as_float(x);
}
__device__ __forceinline__ float dpp_xor3(float v) {   // quad_perm [3,2,1,0]
    int x = __builtin_amdgcn_update_dpp(0, __float_as_int(v), 0x1B, 0xF, 0xF, false);
    return __int_as_float(x);
}
// 4-lane butterfly sum: all 4 lanes of the quad end with the total (bitwise identical)
__device__ __forceinline__ float qsum4(float v) {
    float a = v + dpp_xor1(v);
    return a + dpp_xor2(a);
}

__device__ __forceinline__ float gelu_exact(float x) {
    return 0.5f * x * (1.0f + erff(x * 0.70710678118654752440f));
}

__global__ void __launch_bounds__(256, 1) pinod_kernel(
    const float* __restrict__ expr,
    const float* __restrict__ t_eval,
    const float* __restrict__ enc_w1,
    const float* __restrict__ enc_b1,
    const float* __restrict__ ln_g,
    const float* __restrict__ ln_b,
    const float* __restrict__ enc_w2,
    const float* __restrict__ enc_b2,
    const float* __restrict__ enc_w3,
    const float* __restrict__ enc_b3,
    const float* __restrict__ periods,
    const float* __restrict__ gammav,
    const float* __restrict__ ode_w1,
    const float* __restrict__ ode_b1,
    const float* __restrict__ ode_w2,
    const float* __restrict__ ode_b2,
    const float* __restrict__ dec_w,
    const float* __restrict__ dec_b,
    const float* __restrict__ baseline,
    float* __restrict__ out)
{
    const int tid   = blockIdx.x * 256 + threadIdx.x;
    const int sub   = tid & 3;          // lane within the quad
    const int pair  = tid >> 2;         // quad id: handles elements 2*pair, 2*pair+1
    const int bA    = pair * 2;
    const int bB    = bA + 1;
    const int base8 = sub * 8;          // encoder h-unit slice (8 of 32)
    const int obase = sub * 4;          // ODE hidden-unit slice (4 of 16)

    float* out_eh  = out;                                          // [NB][NT]
    float* out_tr  = out + (size_t)NB * NT;                        // [NT][NB][NS]
    float* out_amp = out + (size_t)NB * NT + (size_t)NT * NB * NS; // [NB][NK]

    const float C = 2.88539008177792681472f;   // 2*log2(e), folded into w1/b1

    // ======== ODE weights as f2 pairs, algebraically folded + pinned ========
    // (loaded ONCE per thread, shared by both elements)
    f2 w1p[NS][2];
    #pragma unroll
    for (int i = 0; i < NS; ++i) {
        float4 wA = *(const float4*)(ode_w1 + i * NOH + obase);
        w1p[i][0].x = C * wA.x; w1p[i][0].y = C * wA.y;
        w1p[i][1].x = C * wA.z; w1p[i][1].y = C * wA.w;
    }
    f2 b1p[2];
    {
        float4 wA = *(const float4*)(ode_b1 + obase);
        b1p[0].x = C * wA.x; b1p[0].y = C * wA.y;
        b1p[1].x = C * wA.z; b1p[1].y = C * wA.w;
    }
    // y = 1 - 2*rc where rc = 1/(exp2(a')+1).  pd = sum_j y_j w2_j + b2
    //   = [0.25*b2 + sum_{local j} w2_j] + sum_{local j} rc_j * (-2 w2_j)
    f2 w2p[4][3];      // -2 * ode_w2 rows (this lane's 4 hidden units)
    f2 hb2p[3];        // 0.25*b2 + sum of this lane's raw w2 rows
    #pragma unroll
    for (int s = 0; s < 3; ++s) {
        float2 w = *(const float2*)(ode_b2 + 2 * s);
        hb2p[s].x = 0.25f * w.x; hb2p[s].y = 0.25f * w.y;
    }
    #pragma unroll
    for (int j = 0; j < 4; ++j) {
        const float2* wp = (const float2*)(ode_w2 + (obase + j) * NS);
        #pragma unroll
        for (int s = 0; s < 3; ++s) {
            float2 w = wp[s];
            hb2p[s].x += w.x;          hb2p[s].y += w.y;
            w2p[j][s].x = -2.0f * w.x; w2p[j][s].y = -2.0f * w.y;
        }
    }
    // linear-dynamics constant pairs: d = (v, -om2*x - 2g*v) + pd
    f2 c1p[3], c2p[3];
    float dw[NK];
    #pragma unroll
    for (int k = 0; k < NK; ++k) {
        float w = 6.28318530717958647693f / uni(periods[k]);
        c1p[k].x = 1.0f; c1p[k].y = uni(-(w * w));
        c2p[k].x = 0.0f; c2p[k].y = uni(-2.0f * gammav[k]);
        dw[k]    = uni(dec_w[k]);
    }
    const float addc = uni(dec_b[0] + baseline[0]);

    #pragma unroll
    for (int i = 0; i < NS; ++i)
        #pragma unroll
        for (int p = 0; p < 2; ++p) PIN_V(w1p[i][p]);
    #pragma unroll
    for (int p = 0; p < 2; ++p) PIN_V(b1p[p]);
    #pragma unroll
    for (int j = 0; j < 4; ++j)
        #pragma unroll
        for (int s = 0; s < 3; ++s) PIN_V(w2p[j][s]);
    #pragma unroll
    for (int s = 0; s < 3; ++s) { PIN_V(hb2p[s]); PIN_V(c1p[s]); PIN_V(c2p[s]); }

    // ================= encoder (4-way split: 8 h-units per lane) ============
    auto encode = [&](int b, f2 (&z)[3]) {
        float h1r[8];
        {
            float4 bv0 = *(const float4*)(enc_b1 + base8);
            float4 bv1 = *(const float4*)(enc_b1 + base8 + 4);
            h1r[0] = bv0.x; h1r[1] = bv0.y; h1r[2] = bv0.z; h1r[3] = bv0.w;
            h1r[4] = bv1.x; h1r[5] = bv1.y; h1r[6] = bv1.z; h1r[7] = bv1.w;
        }
        const float4* xp = (const float4*)(expr + (size_t)b * NT);
        #pragma unroll 1
        for (int t4 = 0; t4 < NT / 4; ++t4) {
            float4 xq = xp[t4];
            float xs[4] = {xq.x, xq.y, xq.z, xq.w};
            #pragma unroll
            for (int u4 = 0; u4 < 4; ++u4) {
                const float* wr = enc_w1 + (t4 * 4 + u4) * NH + base8;
                float x = xs[u4];
                float4 w0 = *(const float4*)(wr);
                float4 w1 = *(const float4*)(wr + 4);
                h1r[0] = fmaf(x, w0.x, h1r[0]); h1r[1] = fmaf(x, w0.y, h1r[1]);
                h1r[2] = fmaf(x, w0.z, h1r[2]); h1r[3] = fmaf(x, w0.w, h1r[3]);
                h1r[4] = fmaf(x, w1.x, h1r[4]); h1r[5] = fmaf(x, w1.y, h1r[5]);
                h1r[6] = fmaf(x, w1.z, h1r[6]); h1r[7] = fmaf(x, w1.w, h1r[7]);
            }
        }
        // layernorm across all 32 (2-stage butterfly) + gelu
        {
            float s = 0.f;
            #pragma unroll
            for (int u = 0; u < 8; ++u) s += h1r[u];
            float mu = qsum4(s) * (1.0f / NH);
            float v = 0.f;
            #pragma unroll
            for (int u = 0; u < 8; ++u) { float d = h1r[u] - mu; v = fmaf(d, d, v); }
            float var = qsum4(v) * (1.0f / NH);
            float rstd = rsqrtf(var + 1e-5f);
            float4 g0 = *(const float4*)(ln_g + base8);
            float4 g1 = *(const float4*)(ln_g + base8 + 4);
            float4 l0 = *(const float4*)(ln_b + base8);
            float4 l1 = *(const float4*)(ln_b + base8 + 4);
            h1r[0] = gelu_exact((h1r[0] - mu) * rstd * g0.x + l0.x);
            h1r[1] = gelu_exact((h1r[1] - mu) * rstd * g0.y + l0.y);
            h1r[2] = gelu_exact((h1r[2] - mu) * rstd * g0.z + l0.z);
            h1r[3] = gelu_exact((h1r[3] - mu) * rstd * g0.w + l0.w);
            h1r[4] = gelu_exact((h1r[4] - mu) * rstd * g1.x + l1.x);
            h1r[5] = gelu_exact((h1r[5] - mu) * rstd * g1.y + l1.y);
            h1r[6] = gelu_exact((h1r[6] - mu) * rstd * g1.z + l1.z);
            h1r[7] = gelu_exact((h1r[7] - mu) * rstd * g1.w + l1.w);
        }
        // h2 = gelu(h1 @ w2 + b2): lane owns j2 in [base8, base8+8)
        float acc[8];
        {
            float4 bv0 = *(const float4*)(enc_b2 + base8);
            float4 bv1 = *(const float4*)(enc_b2 + base8 + 4);
            acc[0] = bv0.x; acc[1] = bv0.y; acc[2] = bv0.z; acc[3] = bv0.w;
            acc[4] = bv1.x; acc[5] = bv1.y; acc[6] = bv1.z; acc[7] = bv1.w;
        }
        #pragma unroll 1
        for (int u = 0; u < 8; ++u) {
            float mine = h1r[u];                 // unit base8     + u
            float o1   = dpp_xor1(mine);         // unit (base8^8) + u
            float o2   = dpp_xor2(mine);         // unit (base8^16)+ u
            float o3   = dpp_xor3(mine);         // unit (base8^24)+ u
            const float* wr0 = enc_w2 + (base8 + u) * NH + base8;
            const float* wr1 = enc_w2 + ((base8 ^ 8) + u) * NH + base8;
            const float* wr2 = enc_w2 + ((base8 ^ 16) + u) * NH + base8;
            const float* wr3 = enc_w2 + ((base8 ^ 24) + u) * NH + base8;
            float4 a0 = *(const float4*)(wr0), a1 = *(const float4*)(wr0 + 4);
            float4 b0 = *(const float4*)(wr1), b1 = *(const float4*)(wr1 + 4);
            float4 c0 = *(const float4*)(wr2), c1 = *(const float4*)(wr2 + 4);
            float4 d0 = *(const float4*)(wr3), d1 = *(const float4*)(wr3 + 4);
            acc[0] = fmaf(mine, a0.x, fmaf(o1, b0.x, fmaf(o2, c0.x, fmaf(o3, d0.x, acc[0]))));
            acc[1] = fmaf(mine, a0.y, fmaf(o1, b0.y, fmaf(o2, c0.y, fmaf(o3, d0.y, acc[1]))));
            acc[2] = fmaf(mine, a0.z, fmaf(o1, b0.z, fmaf(o2, c0.z, fmaf(o3, d0.z, acc[2]))));
            acc[3] = fmaf(mine, a0.w, fmaf(o1, b0.w, fmaf(o2, c0.w, fmaf(o3, d0.w, acc[3]))));
            acc[4] = fmaf(mine, a1.x, fmaf(o1, b1.x, fmaf(o2, c1.x, fmaf(o3, d1.x, acc[4]))));
            acc[5] = fmaf(mine, a1.y, fmaf(o1, b1.y, fmaf(o2, c1.y, fmaf(o3, d1.y, acc[5]))));
            acc[6] = fmaf(mine, a1.z, fmaf(o1, b1.z, fmaf(o2, c1.z, fmaf(o3, d1.z, acc[6]))));
            acc[7] = fmaf(mine, a1.w, fmaf(o1, b1.w, fmaf(o2, c1.w, fmaf(o3, d1.w, acc[7]))));
        }
        // z0 = gelu(acc) @ w3 + b3, 2-stage reduce -> replicated in all 4 lanes
        {
            float zp[NS] = {0.f, 0.f, 0.f, 0.f, 0.f, 0.f};
            #pragma unroll 1
            for (int u = 0; u < 8; ++u) {
                float gm = gelu_exact(acc[u]);
                const float2* wp = (const float2*)(enc_w3 + (base8 + u) * NS);
                float2 w0 = wp[0], w1 = wp[1], w2 = wp[2];
                zp[0] = fmaf(gm, w0.x, zp[0]); zp[1] = fmaf(gm, w0.y, zp[1]);
                zp[2] = fmaf(gm, w1.x, zp[2]); zp[3] = fmaf(gm, w1.y, zp[3]);
                zp[4] = fmaf(gm, w2.x, zp[4]); zp[5] = fmaf(gm, w2.y, zp[5]);
            }
            #pragma unroll
            for (int s = 0; s < 3; ++s) {
                z[s].x = qsum4(zp[2 * s])     + enc_b3[2 * s];
                z[s].y = qsum4(zp[2 * s + 1]) + enc_b3[2 * s + 1];
            }
        }
    };

    f2 zA[3], zB[3];
    encode(bA, zA);
    encode(bB, zB);

    auto deriv = [&](const f2 (&zz)[3], f2 (&d)[3]) {
        // a'[p] = C*(b1 + sum_i z_i w1[i][p]) — first fma inits from b1p (no movs)
        f2 a[2];
        #pragma unroll
        for (int p = 0; p < 2; ++p) {
            PK_FMA_LO_I(a[p], zz[0], w1p[0][p], b1p[p]);
            PK_FMA_HI (a[p], zz[0], w1p[1][p]);
        }
        #pragma unroll
        for (int s = 1; s < 3; ++s) {
            #pragma unroll
            for (int p = 0; p < 2; ++p) {
                PK_FMA_LO(a[p], zz[s], w1p[2 * s][p]);
                PK_FMA_HI(a[p], zz[s], w1p[2 * s + 1][p]);
            }
        }
        // rc = 1/(exp2(a')+1)   (y = 1-2rc folded into w2p/hb2p)
        f2 rc[2];
        #pragma unroll
        for (int p = 0; p < 2; ++p) {
            f2 e; e.x = __builtin_amdgcn_exp2f(a[p].x); e.y = __builtin_amdgcn_exp2f(a[p].y);
            f2 r = e + bc2(1.0f);
            rc[p].x = __builtin_amdgcn_rcpf(r.x); rc[p].y = __builtin_amdgcn_rcpf(r.y);
        }
        // pd[s] = hb2p + sum_{local j} rc_j * w2p[j]  — first fma inits from hb2p
        f2 pd[3];
        #pragma unroll
        for (int s = 0; s < 3; ++s) {
            PK_FMA_LO_I(pd[s], rc[0], w2p[0][s], hb2p[s]);
            PK_FMA_HI (pd[s], rc[0], w2p[1][s]);
            PK_FMA_LO (pd[s], rc[1], w2p[2][s]);
            PK_FMA_HI (pd[s], rc[1], w2p[3][s]);
        }
        // 2-stage cross-lane reduce + packed linear assembly:
        //   t = (zz.y*1 + pd.x, zz.x*(-om2) + pd.y); d = (t.x, zz.y*(-2g)+t.y)
        #pragma unroll
        for (int s = 0; s < 3; ++s) {
            f2 o;
            o.x = dpp_xor1(pd[s].x); o.y = dpp_xor1(pd[s].y);
            pd[s] += o;
            o.x = dpp_xor2(pd[s].x); o.y = dpp_xor2(pd[s].y);
            pd[s] += o;
            f2 t;
            PK_FMA_SWAP_I(t, zz[s], c1p[s], pd[s]);
            d[s] = fma2(zz[s], c2p[s], t);
        }
    };

    // ================= per-t output emit =================
    float ampA[NK], ampB[NK];
    auto emit = [&](int b, const f2 (&z)[3], float (&amp)[NK], int t, bool init) {
        float eh = addc;
        #pragma unroll
        for (int k = 0; k < NK; ++k) {
            float xx = z[k].x;
            amp[k] = init ? (xx * xx) : fmaf(xx, xx, amp[k]);
            eh = fmaf(xx, dw[k], eh);
        }
        float* tp = out_tr + ((size_t)t * NB + b) * NS;
        if (sub == 3) {
            out_eh[(size_t)b * NT + t] = eh;
        } else {
            f2 zsel = (sub == 0) ? z[0] : ((sub == 1) ? z[1] : z[2]);
            float2 sv = {zsel.x, zsel.y};
            *(float2*)(tp + 2 * sub) = sv;
        }
    };

    emit(bA, zA, ampA, 0, true);
    emit(bB, zB, ampB, 0, true);

    // ================= integrate (A and B interleaved for ILP) =============
    float te_prev = t_eval[0];
    #pragma unroll 1
    for (int t = 1; t < NT; ++t) {
        const float te  = t_eval[t];
        const float dt  = te - te_prev;
        te_prev = te;
        const float hh  = dt * (1.0f / NSUB);
        const float hh2 = 0.5f * hh;
        const float hh6 = hh * (1.0f / 6.0f);
        f2 hh2p = bc2(hh2), hhp = bc2(hh), hh6p = bc2(hh6);
        #pragma unroll 1
        for (int ss = 0; ss < NSUB; ++ss) {
            f2 dA[3], dB[3], ztA[3], ztB[3], zsA[3], zsB[3];
            deriv(zA, dA);                                      // k1
            deriv(zB, dB);
            #pragma unroll
            for (int s = 0; s < 3; ++s) {
                zsA[s] = dA[s]; ztA[s] = fma2(hh2p, dA[s], zA[s]);
                zsB[s] = dB[s]; ztB[s] = fma2(hh2p, dB[s], zB[s]);
            }
            deriv(ztA, dA);                                     // k2
            deriv(ztB, dB);
            #pragma unroll
            for (int s = 0; s < 3; ++s) {
                zsA[s] = fma2(bc2(2.f), dA[s], zsA[s]); ztA[s] = fma2(hh2p, dA[s], zA[s]);
                zsB[s] = fma2(bc2(2.f), dB[s], zsB[s]); ztB[s] = fma2(hh2p, dB[s], zB[s]);
            }
            deriv(ztA, dA);                                     // k3
            deriv(ztB, dB);
            #pragma unroll
            for (int s = 0; s < 3; ++s) {
                zsA[s] = fma2(bc2(2.f), dA[s], zsA[s]); ztA[s] = fma2(hhp, dA[s], zA[s]);
                zsB[s] = fma2(bc2(2.f), dB[s], zsB[s]); ztB[s] = fma2(hhp, dB[s], zB[s]);
            }
            deriv(ztA, dA);                                     // k4
            deriv(ztB, dB);
            #pragma unroll
            for (int s = 0; s < 3; ++s) {
                zA[s] = fma2(hh6p, zsA[s] + dA[s], zA[s]);
                zB[s] = fma2(hh6p, zsB[s] + dB[s], zB[s]);
            }
        }
        emit(bA, zA, ampA, t, false);
        emit(bB, zB, ampB, t, false);
    }

    if (sub < 3) {
        float avA = (sub == 0) ? ampA[0] : ((sub == 1) ? ampA[1] : ampA[2]);
        float avB = (sub == 0) ? ampB[0] : ((sub == 1) ? ampB[1] : ampB[2]);
        out_amp[(size_t)bA * NK + sub] = sqrtf(avA * (1.0f / NT));
        out_amp[(size_t)bB * NK + sub] = sqrtf(avB * (1.0f / NT));
    }
}

extern "C" void kernel_launch(void* const* d_in, const int* in_sizes, int n_in,
                              void* d_out, int out_size, void* d_ws, size_t ws_size,
                              hipStream_t stream) {
    pinod_kernel<<<(NB * 2) / 256, 256, 0, stream>>>(
        (const float*)d_in[0],  (const float*)d_in[1],  (const float*)d_in[2],
        (const float*)d_in[3],  (const float*)d_in[4],  (const float*)d_in[5],
        (const float*)d_in[6],  (const float*)d_in[7],  (const float*)d_in[8],
        (const float*)d_in[9],  (const float*)d_in[10], (const float*)d_in[11],
        (const float*)d_in[12], (const float*)d_in[13], (const float*)d_in[14],
        (const float*)d_in[15], (const float*)d_in[16], (const float*)d_in[17],
        (const float*)d_in[18], (float*)d_out);
}

// Round 3
// 291.939 us; speedup vs baseline: 1.2786x; 1.2786x over previous
//
#include <hip/hip_runtime.h>
#include <math.h>

#define NB 32768
#define NT 48
#define NH 32
#define NOH 16
#define NK 3
#define NS 6
#define NSUB 4

typedef float f2 __attribute__((ext_vector_type(2)));

// Force a value/pair to stay live in VGPRs (compiler cannot rematerialize)
#define PIN_V(x) asm volatile("" : "+v"(x))
// Make a wave-uniform float SGPR-resident (legal VGPR->SGPR via readfirstlane)
__device__ __forceinline__ float uni(float x) {
    return __int_as_float(__builtin_amdgcn_readfirstlane(__float_as_int(x)));
}

// packed fma, src0 scalar-broadcast via op_sel (verified semantics in prior session):
//   LO: acc.{x,y} += zp.x * w.{x,y}      HI: acc.{x,y} += zp.y * w.{x,y}
#define PK_FMA_LO(acc, zp, w) \
    asm("v_pk_fma_f32 %0, %1, %2, %0 op_sel:[0,0,0] op_sel_hi:[0,1,1]" \
        : "+v"(acc) : "v"(zp), "v"(w))
#define PK_FMA_HI(acc, zp, w) \
    asm("v_pk_fma_f32 %0, %1, %2, %0 op_sel:[1,0,0] op_sel_hi:[1,1,1]" \
        : "+v"(acc) : "v"(zp), "v"(w))
// init forms: dst = bcast(zp)*w + c   (no accumulator-copy mov)
#define PK_FMA_LO_I(dst, zp, w, c) \
    asm("v_pk_fma_f32 %0, %1, %2, %3 op_sel:[0,0,0] op_sel_hi:[0,1,1]" \
        : "=v"(dst) : "v"(zp), "v"(w), "v"(c))
// mul-init form: dst = bcast(zp.y)*w   (starts the HI chain without a zero/copy)
#define PK_MUL_HI_I(dst, zp, w) \
    asm("v_pk_mul_f32 %0, %1, %2 op_sel:[1,0] op_sel_hi:[1,1]" \
        : "=v"(dst) : "v"(zp), "v"(w))
// swapped src0: lo-result uses zp.hi, hi-result uses zp.lo
#define PK_FMA_SWAP_I(dst, zp, cc, c) \
    asm("v_pk_fma_f32 %0, %1, %2, %3 op_sel:[1,0,0] op_sel_hi:[0,1,1]" \
        : "=v"(dst) : "v"(zp), "v"(cc), "v"(c))

__device__ __forceinline__ f2 fma2(f2 a, f2 b, f2 c) {
    return __builtin_elementwise_fma(a, b, c);
}
__device__ __forceinline__ f2 bc2(float x) { f2 r; r.x = x; r.y = x; return r; }

// partner-lane value via DPP quad_perm [1,0,3,2] (xor lane^1) — VALU pipe
__device__ __forceinline__ float dpp_xor1(float v) {
    int x = __builtin_amdgcn_update_dpp(0, __float_as_int(v), 0xB1, 0xF, 0xF, false);
    return __int_as_float(x);
}
__device__ __forceinline__ float qsum2(float v) { return v + dpp_xor1(v); }

__device__ __forceinline__ float gelu_exact(float x) {
    return 0.5f * x * (1.0f + erff(x * 0.70710678118654752440f));
}

__global__ void __launch_bounds__(256, 1) pinod_kernel(
    const float* __restrict__ expr,
    const float* __restrict__ t_eval,
    const float* __restrict__ enc_w1,
    const float* __restrict__ enc_b1,
    const float* __restrict__ ln_g,
    const float* __restrict__ ln_b,
    const float* __restrict__ enc_w2,
    const float* __restrict__ enc_b2,
    const float* __restrict__ enc_w3,
    const float* __restrict__ enc_b3,
    const float* __restrict__ periods,
    const float* __restrict__ gammav,
    const float* __restrict__ ode_w1,
    const float* __restrict__ ode_b1,
    const float* __restrict__ ode_w2,
    const float* __restrict__ ode_b2,
    const float* __restrict__ dec_w,
    const float* __restrict__ dec_b,
    const float* __restrict__ baseline,
    float* __restrict__ out)
{
    const int tid    = blockIdx.x * 256 + threadIdx.x;
    const int sub    = tid & 1;          // which half of the hidden units
    const int b      = tid >> 1;         // element id (lane pair {2i,2i+1})
    const int base16 = sub * 16;         // encoder h-unit slice
    const int obase  = sub * 8;          // ODE hidden-unit slice

    float* out_eh  = out;                                          // [NB][NT]
    float* out_tr  = out + (size_t)NB * NT;                        // [NT][NB][NS]
    float* out_amp = out + (size_t)NB * NT + (size_t)NT * NB * NS; // [NB][NK]

    const float C = 2.88539008177792681472f;   // 2*log2(e), folded into w1/b1

    // ======== ODE weights as f2 pairs, algebraically folded + pinned ========
    // w1p[i][p] = C * ode_w1[i][obase+2p .. +1]
    f2 w1p[NS][4];
    #pragma unroll
    for (int i = 0; i < NS; ++i) {
        float4 wA = *(const float4*)(ode_w1 + i * NOH + obase);
        float4 wB = *(const float4*)(ode_w1 + i * NOH + obase + 4);
        w1p[i][0].x = C * wA.x; w1p[i][0].y = C * wA.y;
        w1p[i][1].x = C * wA.z; w1p[i][1].y = C * wA.w;
        w1p[i][2].x = C * wB.x; w1p[i][2].y = C * wB.y;
        w1p[i][3].x = C * wB.z; w1p[i][3].y = C * wB.w;
    }
    f2 b1p[4];
    {
        float4 wA = *(const float4*)(ode_b1 + obase);
        float4 wB = *(const float4*)(ode_b1 + obase + 4);
        b1p[0].x = C * wA.x; b1p[0].y = C * wA.y; b1p[1].x = C * wA.z; b1p[1].y = C * wA.w;
        b1p[2].x = C * wB.x; b1p[2].y = C * wB.y; b1p[3].x = C * wB.z; b1p[3].y = C * wB.w;
    }
    // y = 1 - 2*rc where rc = 1/(exp2(a')+1).  pd = sum_j y_j w2_j + b2
    //   = [0.5*b2 + sum_j w2_j] + sum_j rc_j * (-2 w2_j)   (per-lane halves; x2 via dpp sum)
    f2 w2p[8][3];      // -2 * ode_w2 rows
    f2 hb2p[3];        // 0.5*b2 + sum of this lane's raw w2 rows
    #pragma unroll
    for (int s = 0; s < 3; ++s) {
        float2 w = *(const float2*)(ode_b2 + 2 * s);
        hb2p[s].x = 0.5f * w.x; hb2p[s].y = 0.5f * w.y;
    }
    #pragma unroll
    for (int j = 0; j < 8; ++j) {
        const float2* wp = (const float2*)(ode_w2 + (obase + j) * NS);
        #pragma unroll
        for (int s = 0; s < 3; ++s) {
            float2 w = wp[s];
            hb2p[s].x += w.x;          hb2p[s].y += w.y;
            w2p[j][s].x = -2.0f * w.x; w2p[j][s].y = -2.0f * w.y;
        }
    }
    // linear-dynamics constant pairs: d = (v, -om2*x - 2g*v) + pd
    f2 c1p[3], c2p[3];
    float dw[NK];
    #pragma unroll
    for (int k = 0; k < NK; ++k) {
        float w = 6.28318530717958647693f / uni(periods[k]);
        c1p[k].x = 1.0f; c1p[k].y = uni(-(w * w));
        c2p[k].x = 0.0f; c2p[k].y = uni(-2.0f * gammav[k]);
        dw[k]    = uni(dec_w[k]);
    }
    const float addc = uni(dec_b[0] + baseline[0]);

    #pragma unroll
    for (int i = 0; i < NS; ++i)
        #pragma unroll
        for (int p = 0; p < 4; ++p) PIN_V(w1p[i][p]);
    #pragma unroll
    for (int p = 0; p < 4; ++p) PIN_V(b1p[p]);
    #pragma unroll
    for (int j = 0; j < 8; ++j)
        #pragma unroll
        for (int s = 0; s < 3; ++s) PIN_V(w2p[j][s]);
    #pragma unroll
    for (int s = 0; s < 3; ++s) { PIN_V(hb2p[s]); PIN_V(c1p[s]); PIN_V(c2p[s]); }

    // ================= encoder (2-way split: 16 h-units per lane) ============
    float h1r[16];
    #pragma unroll
    for (int q = 0; q < 4; ++q) {
        float4 bv = *(const float4*)(enc_b1 + base16 + 4 * q);
        h1r[4 * q] = bv.x; h1r[4 * q + 1] = bv.y; h1r[4 * q + 2] = bv.z; h1r[4 * q + 3] = bv.w;
    }
    const float4* xp = (const float4*)(expr + (size_t)b * NT);
    #pragma unroll 1
    for (int t4 = 0; t4 < NT / 4; ++t4) {
        float4 xq = xp[t4];
        float xs[4] = {xq.x, xq.y, xq.z, xq.w};
        #pragma unroll
        for (int u4 = 0; u4 < 4; ++u4) {
            const float* wr = enc_w1 + (t4 * 4 + u4) * NH + base16;
            float x = xs[u4];
            #pragma unroll
            for (int q = 0; q < 4; ++q) {
                float4 w = *(const float4*)(wr + 4 * q);
                h1r[4 * q]     = fmaf(x, w.x, h1r[4 * q]);
                h1r[4 * q + 1] = fmaf(x, w.y, h1r[4 * q + 1]);
                h1r[4 * q + 2] = fmaf(x, w.z, h1r[4 * q + 2]);
                h1r[4 * q + 3] = fmaf(x, w.w, h1r[4 * q + 3]);
            }
        }
    }
    // layernorm across all 32 (1-stage cross-lane) + gelu
    {
        float s = 0.f;
        #pragma unroll
        for (int u = 0; u < 16; ++u) s += h1r[u];
        float mu = qsum2(s) * (1.0f / NH);
        float v = 0.f;
        #pragma unroll
        for (int u = 0; u < 16; ++u) { float d = h1r[u] - mu; v = fmaf(d, d, v); }
        float var = qsum2(v) * (1.0f / NH);
        float rstd = rsqrtf(var + 1e-5f);
        #pragma unroll
        for (int q = 0; q < 4; ++q) {
            float4 g = *(const float4*)(ln_g + base16 + 4 * q);
            float4 l = *(const float4*)(ln_b + base16 + 4 * q);
            h1r[4 * q]     = gelu_exact((h1r[4 * q]     - mu) * rstd * g.x + l.x);
            h1r[4 * q + 1] = gelu_exact((h1r[4 * q + 1] - mu) * rstd * g.y + l.y);
            h1r[4 * q + 2] = gelu_exact((h1r[4 * q + 2] - mu) * rstd * g.z + l.z);
            h1r[4 * q + 3] = gelu_exact((h1r[4 * q + 3] - mu) * rstd * g.w + l.w);
        }
    }
    // h2 = gelu(h1 @ w2 + b2): lane owns j2 in [base16, base16+16)
    float acc[16];
    #pragma unroll
    for (int q = 0; q < 4; ++q) {
        float4 bv = *(const float4*)(enc_b2 + base16 + 4 * q);
        acc[4 * q] = bv.x; acc[4 * q + 1] = bv.y; acc[4 * q + 2] = bv.z; acc[4 * q + 3] = bv.w;
    }
    #pragma unroll 1
    for (int u = 0; u < 16; ++u) {
        float mine  = h1r[u];
        float other = dpp_xor1(mine);
        const float* wa = enc_w2 + (base16 + u) * NH + base16;
        const float* wb = enc_w2 + ((16 - base16) + u) * NH + base16;
        #pragma unroll
        for (int q = 0; q < 4; ++q) {
            float4 w1v = *(const float4*)(wa + 4 * q);
            float4 w2v = *(const float4*)(wb + 4 * q);
            acc[4 * q]     = fmaf(mine, w1v.x, fmaf(other, w2v.x, acc[4 * q]));
            acc[4 * q + 1] = fmaf(mine, w1v.y, fmaf(other, w2v.y, acc[4 * q + 1]));
            acc[4 * q + 2] = fmaf(mine, w1v.z, fmaf(other, w2v.z, acc[4 * q + 2]));
            acc[4 * q + 3] = fmaf(mine, w1v.w, fmaf(other, w2v.w, acc[4 * q + 3]));
        }
    }
    // z0 = gelu(acc) @ w3 + b3, 1-stage reduce -> replicated in both lanes
    f2 z[3];
    {
        float zp[NS] = {0.f, 0.f, 0.f, 0.f, 0.f, 0.f};
        #pragma unroll 1
        for (int u = 0; u < 16; ++u) {
            float gm = gelu_exact(acc[u]);
            const float2* wp = (const float2*)(enc_w3 + (base16 + u) * NS);
            float2 w0 = wp[0], w1 = wp[1], w2 = wp[2];
            zp[0] = fmaf(gm, w0.x, zp[0]); zp[1] = fmaf(gm, w0.y, zp[1]);
            zp[2] = fmaf(gm, w1.x, zp[2]); zp[3] = fmaf(gm, w1.y, zp[3]);
            zp[4] = fmaf(gm, w2.x, zp[4]); zp[5] = fmaf(gm, w2.y, zp[5]);
        }
        #pragma unroll
        for (int s = 0; s < 3; ++s) {
            z[s].x = qsum2(zp[2 * s])     + enc_b3[2 * s];
            z[s].y = qsum2(zp[2 * s + 1]) + enc_b3[2 * s + 1];
        }
    }

    auto deriv = [&](const f2 (&zz)[3], f2 (&d)[3]) {
        // a'[p] = C*(b1 + sum_i z_i w1[i][p]) — TWO independent chains per p:
        //   aA[p]: LO terms (z0.x, z1.x, z2.x), init from b1p  (3-deep)
        //   aB[p]: HI terms (z0.y, z1.y, z2.y), init via pk_mul (3-deep)
        // Halves the dep-chain depth; merge is one pk_add.
        f2 aA[4], aB[4];
        #pragma unroll
        for (int p = 0; p < 4; ++p) {
            PK_FMA_LO_I(aA[p], zz[0], w1p[0][p], b1p[p]);
            PK_MUL_HI_I(aB[p], zz[0], w1p[1][p]);
        }
        #pragma unroll
        for (int s = 1; s < 3; ++s) {
            #pragma unroll
            for (int p = 0; p < 4; ++p) {
                PK_FMA_LO(aA[p], zz[s], w1p[2 * s][p]);
                PK_FMA_HI(aB[p], zz[s], w1p[2 * s + 1][p]);
            }
        }
        // merge -> exp2 -> +1 -> rcp, p-ascending so pair 0's trans ops issue
        // while pairs 1..3 are still accumulating (trans-latency overlap)
        f2 rc[4];
        #pragma unroll
        for (int p = 0; p < 4; ++p) {
            f2 a = aA[p] + aB[p];
            f2 e; e.x = __builtin_amdgcn_exp2f(a.x); e.y = __builtin_amdgcn_exp2f(a.y);
            f2 r = e + bc2(1.0f);
            rc[p].x = __builtin_amdgcn_rcpf(r.x); rc[p].y = __builtin_amdgcn_rcpf(r.y);
        }
        // pd[s] = hb2p + sum_j rc_j * w2p[j] — TWO chains per s (4-deep each):
        //   pdA: units {0,2,4,6} (LO of rc[0..3]), init from hb2p
        //   pdB: units {1,3,5,7} (HI of rc[0..3]), init via pk_mul
        // pdA/pdB start as soon as rc[0] is ready, overlapping rc[2..3] trans.
        f2 pdA[3], pdB[3];
        #pragma unroll
        for (int s = 0; s < 3; ++s) {
            PK_FMA_LO_I(pdA[s], rc[0], w2p[0][s], hb2p[s]);
            PK_MUL_HI_I(pdB[s], rc[0], w2p[1][s]);
        }
        #pragma unroll
        for (int p = 1; p < 4; ++p) {
            #pragma unroll
            for (int s = 0; s < 3; ++s) {
                PK_FMA_LO(pdA[s], rc[p], w2p[2 * p][s]);
                PK_FMA_HI(pdB[s], rc[p], w2p[2 * p + 1][s]);
            }
        }
        // merge + cross-lane reduce + packed linear assembly:
        //   t = (zz.y*1 + pd.x, zz.x*(-om2) + pd.y); d = (t.x, zz.y*(-2g)+t.y)
        #pragma unroll
        for (int s = 0; s < 3; ++s) {
            f2 pd = pdA[s] + pdB[s];
            f2 o; o.x = dpp_xor1(pd.x); o.y = dpp_xor1(pd.y);
            pd += o;
            f2 t;
            PK_FMA_SWAP_I(t, zz[s], c1p[s], pd);
            d[s] = fma2(zz[s], c2p[s], t);
        }
    };

    // ================= t = 0 outputs =================
    float amp[NK];
    {
        float eh = addc;
        #pragma unroll
        for (int k = 0; k < NK; ++k) {
            float xx = z[k].x;
            amp[k] = xx * xx;
            eh = fmaf(xx, dw[k], eh);
        }
        float* tp = out_tr + (size_t)b * NS;
        if (sub == 0) {
            out_eh[(size_t)b * NT] = eh;
            float2 s0 = {z[0].x, z[0].y}, s1 = {z[1].x, z[1].y};
            *(float2*)tp = s0; *(float2*)(tp + 2) = s1;
        } else {
            float2 s2 = {z[2].x, z[2].y};
            *(float2*)(tp + 4) = s2;
        }
    }

    // ================= integrate =================
    float te_prev = t_eval[0];
    #pragma unroll 1
    for (int t = 1; t < NT; ++t) {
        const float te  = t_eval[t];
        const float dt  = te - te_prev;
        te_prev = te;
        const float hh  = dt * (1.0f / NSUB);
        const float hh2 = 0.5f * hh;
        const float hh6 = hh * (1.0f / 6.0f);
        f2 hh2p = bc2(hh2), hhp = bc2(hh), hh6p = bc2(hh6);
        #pragma unroll 1
        for (int ss = 0; ss < NSUB; ++ss) {
            f2 d[3], zt[3], zs[3];
            deriv(z, d);                                        // k1
            #pragma unroll
            for (int s = 0; s < 3; ++s) { zs[s] = d[s]; zt[s] = fma2(hh2p, d[s], z[s]); }
            deriv(zt, d);                                       // k2
            #pragma unroll
            for (int s = 0; s < 3; ++s) { zs[s] = fma2(bc2(2.f), d[s], zs[s]); zt[s] = fma2(hh2p, d[s], z[s]); }
            deriv(zt, d);                                       // k3
            #pragma unroll
            for (int s = 0; s < 3; ++s) { zs[s] = fma2(bc2(2.f), d[s], zs[s]); zt[s] = fma2(hhp, d[s], z[s]); }
            deriv(zt, d);                                       // k4
            #pragma unroll
            for (int s = 0; s < 3; ++s) z[s] = fma2(hh6p, zs[s] + d[s], z[s]);
        }
        float eh = addc;
        #pragma unroll
        for (int k = 0; k < NK; ++k) {
            float xx = z[k].x;
            amp[k] = fmaf(xx, xx, amp[k]);
            eh = fmaf(xx, dw[k], eh);
        }
        float* tp = out_tr + ((size_t)t * NB + b) * NS;
        if (sub == 0) {
            out_eh[(size_t)b * NT + t] = eh;
            float2 s0 = {z[0].x, z[0].y}, s1 = {z[1].x, z[1].y};
            *(float2*)tp = s0; *(float2*)(tp + 2) = s1;
        } else {
            float2 s2 = {z[2].x, z[2].y};
            *(float2*)(tp + 4) = s2;
        }
    }

    if (sub == 0) {
        out_amp[(size_t)b * NK]     = sqrtf(amp[0] * (1.0f / NT));
        out_amp[(size_t)b * NK + 1] = sqrtf(amp[1] * (1.0f / NT));
    } else {
        out_amp[(size_t)b * NK + 2] = sqrtf(amp[2] * (1.0f / NT));
    }
}

extern "C" void kernel_launch(void* const* d_in, const int* in_sizes, int n_in,
                              void* d_out, int out_size, void* d_ws, size_t ws_size,
                              hipStream_t stream) {
    pinod_kernel<<<(NB * 2) / 256, 256, 0, stream>>>(
        (const float*)d_in[0],  (const float*)d_in[1],  (const float*)d_in[2],
        (const float*)d_in[3],  (const float*)d_in[4],  (const float*)d_in[5],
        (const float*)d_in[6],  (const float*)d_in[7],  (const float*)d_in[8],
        (const float*)d_in[9],  (const float*)d_in[10], (const float*)d_in[11],
        (const float*)d_in[12], (const float*)d_in[13], (const float*)d_in[14],
        (const float*)d_in[15], (const float*)d_in[16], (const float*)d_in[17],
        (const float*)d_in[18], (float*)d_out);
}